// Round 4
// baseline (727.747 us; speedup 1.0000x reference)
//
#include <hip/hip_runtime.h>
#include <hip/hip_bf16.h>

// GPT-2 transformer block, MI355X bf16-MFMA. Round 4:
//  - attention restructured: barrier-free, LDS-minimal.
//    * m=0 streaming softmax (R3) makes k-tiles associative -> each wave owns
//      32 q-rows and loops its causal k-range independently; NO __syncthreads.
//    * Q/K/V MFMA fragments loaded DIRECTLY global->VGPR (coalesced 64B lines,
//      L2-hot): no K/V staging in LDS.
//    * S computed TRANSPOSED (S^T = K x Q^T) so the C-layout gives each lane 4
//      consecutive k for fixed q -> P stored to LDS with packed ds_write_b64.
//    * LDS holds only P (4 waves x 32 rows x 72 = 18.4 KB).
//    * l (softmax denom) via ones-B MFMA: rows match O accumulator rows.

typedef __attribute__((ext_vector_type(8))) short bf16x8;  // MFMA A/B frag
typedef __attribute__((ext_vector_type(4))) float f32x4;   // MFMA C/D frag

__device__ __forceinline__ float b2f(unsigned short u) {
  return __uint_as_float(((unsigned int)u) << 16);
}
__device__ __forceinline__ unsigned short f2b(float f) {  // RNE
  unsigned int u = __float_as_uint(f);
  u += 0x7fffu + ((u >> 16) & 1u);
  return (unsigned short)(u >> 16);
}
__device__ __forceinline__ void gload_lds16(const unsigned short* g, unsigned short* l) {
  __builtin_amdgcn_global_load_lds((const __attribute__((address_space(1))) void*)g,
                                   (__attribute__((address_space(3))) void*)l, 16, 0, 0);
}

// ---------------- fp32 -> bf16 elementwise ----------------
__global__ __launch_bounds__(256) void cvt_bf16(const float* __restrict__ in,
                                                unsigned short* __restrict__ out, long n) {
  long i = ((long)blockIdx.x * 256 + threadIdx.x) * 4;
  if (i >= n) return;
  float4 v = *(const float4*)(in + i);
  *(ushort4*)(out + i) = make_ushort4(f2b(v.x), f2b(v.y), f2b(v.z), f2b(v.w));
}

// ---------------- transpose fp32 [R,C] -> bf16 [C,R] ----------------
__global__ __launch_bounds__(256) void transpose_bf16(const float* __restrict__ in,
                                                      unsigned short* __restrict__ out,
                                                      int R, int C) {
  __shared__ float tile[32][33];
  int c0 = blockIdx.x * 32, r0 = blockIdx.y * 32;
  for (int i = threadIdx.y; i < 32; i += 8)
    tile[i][threadIdx.x] = in[(long)(r0 + i) * C + c0 + threadIdx.x];
  __syncthreads();
  for (int i = threadIdx.y; i < 32; i += 8)
    out[(long)(c0 + i) * R + r0 + threadIdx.x] = f2b(tile[threadIdx.x][i]);
}

// ---------------- bf16 MFMA GEMM (m97 recipe) ----------------
// EPI: 0=f32 out, 1=bf16 out, 2=bf16+relu,
//      3=qkv split: gn<2048 -> qk[m][2048] (q cols scaled by 0.125*log2e),
//                   gn>=2048 -> vt[b,h,s,t] packed ushort4 scatter.
template <int EPI>
__global__ __launch_bounds__(256) void gemm_bf16(const unsigned short* __restrict__ A,
                                                 const unsigned short* __restrict__ Bt,
                                                 const float* __restrict__ bias,
                                                 void* __restrict__ Cout,
                                                 int M, int N, int K) {
  __shared__ unsigned short As[128 * 32];
  __shared__ unsigned short Bs[128 * 32];
  int t = threadIdx.x;
  int bm = blockIdx.x * 128, bn = blockIdx.y * 128;
  int w = t >> 6, lane = t & 63;
  int wr = w >> 1, wc = w & 1, quad = lane >> 4, l16 = lane & 15;
  int srow = t >> 2, scol = (t & 3) * 8;

  const unsigned short* Ap = A + (long)(bm + srow) * K + scol;
  const unsigned short* Bp = Bt + (long)(bn + srow) * K + scol;
  unsigned short* Asw = As + w * 512;
  unsigned short* Bsw = Bs + w * 512;

  f32x4 acc[4][4] = {};

  for (int k0 = 0; k0 < K; k0 += 32) {
    __syncthreads();
    gload_lds16(Ap + k0, Asw);
    gload_lds16(Ap + (long)64 * K + k0, Asw + 2048);
    gload_lds16(Bp + k0, Bsw);
    gload_lds16(Bp + (long)64 * K + k0, Bsw + 2048);
    __syncthreads();
    bf16x8 af[4], bfr[4];
#pragma unroll
    for (int i = 0; i < 4; ++i)
      af[i] = *(const bf16x8*)(As + (wr * 64 + i * 16 + l16) * 32 + quad * 8);
#pragma unroll
    for (int j = 0; j < 4; ++j)
      bfr[j] = *(const bf16x8*)(Bs + (wc * 64 + j * 16 + l16) * 32 + quad * 8);
#pragma unroll
    for (int i = 0; i < 4; ++i)
#pragma unroll
      for (int j = 0; j < 4; ++j)
        acc[i][j] = __builtin_amdgcn_mfma_f32_16x16x32_bf16(af[i], bfr[j], acc[i][j], 0, 0, 0);
  }

#pragma unroll
  for (int i = 0; i < 4; ++i) {
#pragma unroll
    for (int j = 0; j < 4; ++j) {
      int gn = bn + wc * 64 + j * 16 + l16;
      float bv = bias[gn];
      if (EPI == 3 && gn >= 2048) {
        int h = (gn >> 6) & 15, s = gn & 63;
        int gm0 = bm + wr * 64 + i * 16 + quad * 4;
        int b = gm0 >> 11, tt0 = gm0 & 2047;
        unsigned short* vt = (unsigned short*)Cout + 16777216L;
        ushort4 us;
        us.x = f2b(acc[i][j][0] + bv);
        us.y = f2b(acc[i][j][1] + bv);
        us.z = f2b(acc[i][j][2] + bv);
        us.w = f2b(acc[i][j][3] + bv);
        *(ushort4*)(vt + (((long)(b * 16 + h)) * 64 + s) * 2048 + tt0) = us;
      } else {
#pragma unroll
        for (int r = 0; r < 4; ++r) {
          int gm = bm + wr * 64 + i * 16 + quad * 4 + r;
          float v = acc[i][j][r] + bv;
          if (EPI == 2) v = fmaxf(v, 0.f);
          if (EPI == 0) {
            ((float*)Cout)[(long)gm * N + gn] = v;
          } else if (EPI == 1 || EPI == 2) {
            ((unsigned short*)Cout)[(long)gm * N + gn] = f2b(v);
          } else {  // EPI==3, q/k rows
            float sc = (gn < 1024) ? 0.18033688011112042f : 1.0f;  // 0.125*log2(e)
            ((unsigned short*)Cout)[(long)gm * 2048 + gn] = f2b(v * sc);
          }
        }
      }
    }
  }
}

// ---------------- barrier-free MFMA flash attention --------------------------
// qk[m][2048] (q cols 0..1023 pre-scaled by 0.125*log2e, k cols 1024..2047),
// vt[b,h,s,t] at elem offset 16M. Grid (T/128, H, B), 256 thr = 4 independent
// waves; wave w owns q rows [q0, q0+32). P = exp2(S) (m=0 streaming softmax).
__global__ __launch_bounds__(256) void attn_mfma(const unsigned short* __restrict__ qkv,
                                                 unsigned short* __restrict__ outp) {
  const int LD = 72;
  __shared__ __align__(16) unsigned short Ps[4][32 * LD];
  int h = blockIdx.y, b = blockIdx.z;
  int t = threadIdx.x;
  int w = t >> 6, lane = t & 63, quad = lane >> 4, l16 = lane & 15;
  int q0 = blockIdx.x * 128 + w * 32;
  const unsigned short* qg = qkv + (long)(b * 2048) * 2048 + h * 64;
  const unsigned short* kg = qg + 1024;
  const unsigned short* vg = qkv + 16777216L + (((long)(b * 16 + h)) * 64) * 2048;
  unsigned short* Pw = &Ps[w][0];

  // Q frags (B-operand for S^T): [n=l16 -> q][k=quad*8+j -> s], resident in regs
  bf16x8 qf[2][2];
#pragma unroll
  for (int g = 0; g < 2; ++g)
#pragma unroll
    for (int ks = 0; ks < 2; ++ks)
      qf[g][ks] = *(const bf16x8*)(qg + (long)(q0 + g * 16 + l16) * 2048 + ks * 32 + quad * 8);

  f32x4 oacc[2][4] = {};
  f32x4 lacc[2] = {};
  const short ONE = 0x3F80;
  bf16x8 ones = {ONE, ONE, ONE, ONE, ONE, ONE, ONE, ONE};

  int lastkt = (q0 + 31) >> 6;
  for (int kt = 0; kt <= lastkt; ++kt) {
    bool diag = (kt == lastkt);
    int rgmax = (diag && ((q0 & 63) == 0)) ? 2 : 4;  // aligned wave: upper half all-masked
    int kcmax = rgmax >> 1;

    // K frags (A-operand): [m=l16 -> k-row][k=quad*8+j -> s]
    bf16x8 kf[4][2];
#pragma unroll
    for (int rg = 0; rg < 4; ++rg) {
      if (rg >= rgmax) break;
#pragma unroll
      for (int ks = 0; ks < 2; ++ks)
        kf[rg][ks] = *(const bf16x8*)(kg + (long)(kt * 64 + rg * 16 + l16) * 2048 + ks * 32 + quad * 8);
    }
    // V frags (B-operand for PV): [n=l16 -> s][k=quad*8+j -> t]
    bf16x8 vf[4][2];
#pragma unroll
    for (int sg = 0; sg < 4; ++sg)
#pragma unroll
      for (int kc = 0; kc < 2; ++kc) {
        if (kc >= kcmax) break;
        vf[sg][kc] = *(const bf16x8*)(vg + (long)(sg * 16 + l16) * 2048 + kt * 64 + kc * 32 + quad * 8);
      }

    // S^T = K x Q^T : C col = q (l16), rows = k (quad*4+r) -> packed b64 P write
#pragma unroll
    for (int rg = 0; rg < 4; ++rg) {
      if (rg >= rgmax) break;
#pragma unroll
      for (int cg = 0; cg < 2; ++cg) {
        f32x4 st = {};
#pragma unroll
        for (int ks = 0; ks < 2; ++ks)
          st = __builtin_amdgcn_mfma_f32_16x16x32_bf16(kf[rg][ks], qf[cg][ks], st, 0, 0, 0);
        if (diag) {
          int qg_ = q0 + cg * 16 + l16;
          int kb = kt * 64 + rg * 16 + quad * 4;
#pragma unroll
          for (int r = 0; r < 4; ++r)
            if (kb + r > qg_) st[r] = -1e30f;
        }
        unsigned int lo = ((unsigned int)f2b(exp2f(st[1])) << 16) | f2b(exp2f(st[0]));
        unsigned int hi = ((unsigned int)f2b(exp2f(st[3])) << 16) | f2b(exp2f(st[2]));
        *(uint2*)(Pw + (cg * 16 + l16) * LD + rg * 16 + quad * 4) = make_uint2(lo, hi);
      }
    }

    // O += P V ; l += P * ones   (wave-private LDS; no barrier needed)
#pragma unroll
    for (int g = 0; g < 2; ++g)
#pragma unroll
      for (int kc = 0; kc < 2; ++kc) {
        if (kc >= kcmax) break;
        bf16x8 ap = *(const bf16x8*)(Pw + (g * 16 + l16) * LD + kc * 32 + quad * 8);
        lacc[g] = __builtin_amdgcn_mfma_f32_16x16x32_bf16(ap, ones, lacc[g], 0, 0, 0);
#pragma unroll
        for (int sg = 0; sg < 4; ++sg)
          oacc[g][sg] = __builtin_amdgcn_mfma_f32_16x16x32_bf16(ap, vf[sg][kc], oacc[g][sg], 0, 0, 0);
      }
  }

#pragma unroll
  for (int g = 0; g < 2; ++g)
#pragma unroll
    for (int r = 0; r < 4; ++r) {
      float invl = 1.f / lacc[g][r];
      int row = q0 + g * 16 + quad * 4 + r;
      unsigned short* op = outp + ((long)(b * 2048 + row)) * 1024 + h * 64;
#pragma unroll
      for (int sg = 0; sg < 4; ++sg) op[sg * 16 + l16] = f2b(oacc[g][sg][r] * invl);
    }
}

// ---------------- residual + LayerNorm ----------------
__global__ __launch_bounds__(256) void ln_kernel(const float* __restrict__ a,
                                                 const float* __restrict__ res,
                                                 const float* __restrict__ gam,
                                                 const float* __restrict__ bet,
                                                 float* __restrict__ outf,
                                                 unsigned short* __restrict__ outb) {
  int row = blockIdx.x, t = threadIdx.x;
  float4 av = *(const float4*)(a + (long)row * 1024 + t * 4);
  float4 rv = *(const float4*)(res + (long)row * 1024 + t * 4);
  float v0 = av.x + rv.x, v1 = av.y + rv.y, v2 = av.z + rv.z, v3 = av.w + rv.w;
  float s = v0 + v1 + v2 + v3;
  float ss = v0 * v0 + v1 * v1 + v2 * v2 + v3 * v3;
#pragma unroll
  for (int off = 32; off >= 1; off >>= 1) {
    s += __shfl_down(s, off);
    ss += __shfl_down(ss, off);
  }
  __shared__ float sb[4], ssb[4];
  __shared__ float mean_s, inv_s;
  int w = t >> 6, lane = t & 63;
  if (lane == 0) { sb[w] = s; ssb[w] = ss; }
  __syncthreads();
  if (t == 0) {
    float S = sb[0] + sb[1] + sb[2] + sb[3];
    float SS = ssb[0] + ssb[1] + ssb[2] + ssb[3];
    float mean = S * (1.f / 1024.f);
    float var = SS * (1.f / 1024.f) - mean * mean;
    mean_s = mean;
    inv_s = rsqrtf(var + 1e-5f);
  }
  __syncthreads();
  float mean = mean_s, inv = inv_s;
  int c = t * 4;
  float4 gv = *(const float4*)(gam + c);
  float4 bv = *(const float4*)(bet + c);
  float y0 = (v0 - mean) * inv * gv.x + bv.x;
  float y1 = (v1 - mean) * inv * gv.y + bv.y;
  float y2 = (v2 - mean) * inv * gv.z + bv.z;
  float y3 = (v3 - mean) * inv * gv.w + bv.w;
  *(float4*)(outf + (long)row * 1024 + c) = make_float4(y0, y1, y2, y3);
  if (outb) {
    *(ushort4*)(outb + (long)row * 1024 + c) = make_ushort4(f2b(y0), f2b(y1), f2b(y2), f2b(y3));
  }
}

extern "C" void kernel_launch(void* const* d_in, const int* in_sizes, int n_in,
                              void* d_out, int out_size, void* d_ws, size_t ws_size,
                              hipStream_t stream) {
  const float* x      = (const float*)d_in[0];
  const float* w_attn = (const float*)d_in[1];
  const float* b_attn = (const float*)d_in[2];
  const float* w_proj = (const float*)d_in[3];
  const float* b_proj = (const float*)d_in[4];
  const float* ln1_g  = (const float*)d_in[5];
  const float* ln1_b  = (const float*)d_in[6];
  const float* w_ff1  = (const float*)d_in[7];
  const float* b_ff1  = (const float*)d_in[8];
  const float* w_ff2  = (const float*)d_in[9];
  const float* b_ff2  = (const float*)d_in[10];
  const float* ln2_g  = (const float*)d_in[11];
  const float* ln2_b  = (const float*)d_in[12];

  const long M = 8192, E = 1024;
  char* ws = (char*)d_ws;
  unsigned short* xb   = (unsigned short*)ws; ws += M * E * 2;           // 16 MiB
  unsigned short* wTa  = (unsigned short*)ws; ws += 3072L * 1024 * 2;    // 6
  unsigned short* wTp  = (unsigned short*)ws; ws += 1024L * 1024 * 2;    // 2
  unsigned short* wTf1 = (unsigned short*)ws; ws += 4096L * 1024 * 2;    // 8
  unsigned short* wTf2 = (unsigned short*)ws; ws += 4096L * 1024 * 2;    // 8
  unsigned short* qkvb = (unsigned short*)ws; ws += M * 3072 * 2;        // 48 (qk rows 32 MiB | vt 16 MiB)
  unsigned short* attb = (unsigned short*)ws; ws += M * E * 2;           // 16
  float* a1f = (float*)ws; ws += M * E * 4;                              // 32
  float* x1f = (float*)ws; ws += M * E * 4;                              // 32
  unsigned short* x1b = (unsigned short*)ws; ws += M * E * 2;            // 16  => 184 MiB
  unsigned short* hb = qkvb;   // overlays consumed qkv+attb space
  float* f2 = a1f;

  cvt_bf16<<<dim3((M * E) / 4 / 256), dim3(256), 0, stream>>>(x, xb, M * E);
  transpose_bf16<<<dim3(3072 / 32, 1024 / 32), dim3(32, 8), 0, stream>>>(w_attn, wTa, 1024, 3072);
  transpose_bf16<<<dim3(1024 / 32, 1024 / 32), dim3(32, 8), 0, stream>>>(w_proj, wTp, 1024, 1024);
  transpose_bf16<<<dim3(4096 / 32, 1024 / 32), dim3(32, 8), 0, stream>>>(w_ff1, wTf1, 1024, 4096);
  transpose_bf16<<<dim3(1024 / 32, 4096 / 32), dim3(32, 8), 0, stream>>>(w_ff2, wTf2, 4096, 1024);
  // qkv projection, attention-layout epilogue
  gemm_bf16<3><<<dim3(64, 24), dim3(256), 0, stream>>>(xb, wTa, b_attn, qkvb, 8192, 3072, 1024);
  // barrier-free MFMA flash attention
  attn_mfma<<<dim3(16, 16, 4), dim3(256), 0, stream>>>(qkvb, attb);
  // attn output projection
  gemm_bf16<0><<<dim3(64, 8), dim3(256), 0, stream>>>(attb, wTp, b_proj, a1f, 8192, 1024, 1024);
  ln_kernel<<<dim3(8192), dim3(256), 0, stream>>>(a1f, x, ln1_g, ln1_b, x1f, x1b);
  gemm_bf16<2><<<dim3(64, 32), dim3(256), 0, stream>>>(x1b, wTf1, b_ff1, hb, 8192, 4096, 1024);
  gemm_bf16<0><<<dim3(64, 8), dim3(256), 0, stream>>>(hb, wTf2, b_ff2, f2, 8192, 1024, 4096);
  ln_kernel<<<dim3(8192), dim3(256), 0, stream>>>(f2, x1f, ln2_g, ln2_b, (float*)d_out, nullptr);
}

// Round 5
// 632.857 us; speedup vs baseline: 1.1499x; 1.1499x over previous
//
#include <hip/hip_runtime.h>
#include <hip/hip_bf16.h>

// GPT-2 transformer block, MI355X bf16-MFMA. Round 5:
//  - attention: back to R3's LDS-staged, barrier'd structure (R4's direct
//    global->VGPR frags put L2 latency on the MFMA chain and regressed).
//    New on top of R3:
//    * S computed transposed (S^T = K x Q^T): P written to LDS as packed
//      ds_write_b64 (8/tile vs 16 ds_write_b16), wave-private rows.
//    * diagonal-tile work skipping: wave w computes only rg<=w S-subtiles and
//      ceil((w+1)/2) PV k-chunks (one b64 zero-pad when odd), mask condition
//      collapses to quad*4+r > l16.
//    * heaviest-first q-block ordering (qi = 31 - blockIdx.x) for occupancy.
//  - m=0 streaming softmax (scores O(1): no overflow), l via ones-B MFMA.
//  - GEMMs: m97 recipe (global_load_lds w=16, 128^2 tile, BK=32), unchanged.

typedef __attribute__((ext_vector_type(8))) short bf16x8;  // MFMA A/B frag
typedef __attribute__((ext_vector_type(4))) float f32x4;   // MFMA C/D frag

__device__ __forceinline__ float b2f(unsigned short u) {
  return __uint_as_float(((unsigned int)u) << 16);
}
__device__ __forceinline__ unsigned short f2b(float f) {  // RNE
  unsigned int u = __float_as_uint(f);
  u += 0x7fffu + ((u >> 16) & 1u);
  return (unsigned short)(u >> 16);
}
__device__ __forceinline__ void gload_lds16(const unsigned short* g, unsigned short* l) {
  __builtin_amdgcn_global_load_lds((const __attribute__((address_space(1))) void*)g,
                                   (__attribute__((address_space(3))) void*)l, 16, 0, 0);
}

// ---------------- fp32 -> bf16 elementwise ----------------
__global__ __launch_bounds__(256) void cvt_bf16(const float* __restrict__ in,
                                                unsigned short* __restrict__ out, long n) {
  long i = ((long)blockIdx.x * 256 + threadIdx.x) * 4;
  if (i >= n) return;
  float4 v = *(const float4*)(in + i);
  *(ushort4*)(out + i) = make_ushort4(f2b(v.x), f2b(v.y), f2b(v.z), f2b(v.w));
}

// ---------------- transpose fp32 [R,C] -> bf16 [C,R] ----------------
__global__ __launch_bounds__(256) void transpose_bf16(const float* __restrict__ in,
                                                      unsigned short* __restrict__ out,
                                                      int R, int C) {
  __shared__ float tile[32][33];
  int c0 = blockIdx.x * 32, r0 = blockIdx.y * 32;
  for (int i = threadIdx.y; i < 32; i += 8)
    tile[i][threadIdx.x] = in[(long)(r0 + i) * C + c0 + threadIdx.x];
  __syncthreads();
  for (int i = threadIdx.y; i < 32; i += 8)
    out[(long)(c0 + i) * R + r0 + threadIdx.x] = f2b(tile[threadIdx.x][i]);
}

// ---------------- bf16 MFMA GEMM (m97 recipe) ----------------
// EPI: 0=f32 out, 1=bf16 out, 2=bf16+relu,
//      3=qkv split: gn<2048 -> qk[m][2048] (q cols scaled by 0.125*log2e),
//                   gn>=2048 -> vt[b,h,s,t] packed ushort4 scatter.
template <int EPI>
__global__ __launch_bounds__(256) void gemm_bf16(const unsigned short* __restrict__ A,
                                                 const unsigned short* __restrict__ Bt,
                                                 const float* __restrict__ bias,
                                                 void* __restrict__ Cout,
                                                 int M, int N, int K) {
  __shared__ unsigned short As[128 * 32];
  __shared__ unsigned short Bs[128 * 32];
  int t = threadIdx.x;
  int bm = blockIdx.x * 128, bn = blockIdx.y * 128;
  int w = t >> 6, lane = t & 63;
  int wr = w >> 1, wc = w & 1, quad = lane >> 4, l16 = lane & 15;
  int srow = t >> 2, scol = (t & 3) * 8;

  const unsigned short* Ap = A + (long)(bm + srow) * K + scol;
  const unsigned short* Bp = Bt + (long)(bn + srow) * K + scol;
  unsigned short* Asw = As + w * 512;
  unsigned short* Bsw = Bs + w * 512;

  f32x4 acc[4][4] = {};

  for (int k0 = 0; k0 < K; k0 += 32) {
    __syncthreads();
    gload_lds16(Ap + k0, Asw);
    gload_lds16(Ap + (long)64 * K + k0, Asw + 2048);
    gload_lds16(Bp + k0, Bsw);
    gload_lds16(Bp + (long)64 * K + k0, Bsw + 2048);
    __syncthreads();
    bf16x8 af[4], bfr[4];
#pragma unroll
    for (int i = 0; i < 4; ++i)
      af[i] = *(const bf16x8*)(As + (wr * 64 + i * 16 + l16) * 32 + quad * 8);
#pragma unroll
    for (int j = 0; j < 4; ++j)
      bfr[j] = *(const bf16x8*)(Bs + (wc * 64 + j * 16 + l16) * 32 + quad * 8);
#pragma unroll
    for (int i = 0; i < 4; ++i)
#pragma unroll
      for (int j = 0; j < 4; ++j)
        acc[i][j] = __builtin_amdgcn_mfma_f32_16x16x32_bf16(af[i], bfr[j], acc[i][j], 0, 0, 0);
  }

#pragma unroll
  for (int i = 0; i < 4; ++i) {
#pragma unroll
    for (int j = 0; j < 4; ++j) {
      int gn = bn + wc * 64 + j * 16 + l16;
      float bv = bias[gn];
      if (EPI == 3 && gn >= 2048) {
        int h = (gn >> 6) & 15, s = gn & 63;
        int gm0 = bm + wr * 64 + i * 16 + quad * 4;
        int b = gm0 >> 11, tt0 = gm0 & 2047;
        unsigned short* vt = (unsigned short*)Cout + 16777216L;
        ushort4 us;
        us.x = f2b(acc[i][j][0] + bv);
        us.y = f2b(acc[i][j][1] + bv);
        us.z = f2b(acc[i][j][2] + bv);
        us.w = f2b(acc[i][j][3] + bv);
        *(ushort4*)(vt + (((long)(b * 16 + h)) * 64 + s) * 2048 + tt0) = us;
      } else {
#pragma unroll
        for (int r = 0; r < 4; ++r) {
          int gm = bm + wr * 64 + i * 16 + quad * 4 + r;
          float v = acc[i][j][r] + bv;
          if (EPI == 2) v = fmaxf(v, 0.f);
          if (EPI == 0) {
            ((float*)Cout)[(long)gm * N + gn] = v;
          } else if (EPI == 1 || EPI == 2) {
            ((unsigned short*)Cout)[(long)gm * N + gn] = f2b(v);
          } else {  // EPI==3, q/k rows
            float sc = (gn < 1024) ? 0.18033688011112042f : 1.0f;  // 0.125*log2(e)
            ((unsigned short*)Cout)[(long)gm * 2048 + gn] = f2b(v * sc);
          }
        }
      }
    }
  }
}

// ---------------- MFMA flash attention (staged, transposed-S) ----------------
// qk[m][2048] (q cols 0..1023 pre-scaled by 0.125*log2e, k cols 1024..2047),
// vt[b,h,s,t] at elem offset 16M. Grid (T/64, H, B), 256 thr = 4 waves; wave w
// owns q rows [w*16, w*16+16). P = exp2(S), l via ones-B MFMA.
__global__ __launch_bounds__(256) void attn_mfma(const unsigned short* __restrict__ qkv,
                                                 unsigned short* __restrict__ outp) {
  const int LD = 72;  // 144 B row stride, 16B-aligned rows
  __shared__ __align__(16) unsigned short Qs[64 * LD];
  __shared__ __align__(16) unsigned short Ks[64 * LD];
  __shared__ __align__(16) unsigned short Vts[64 * LD];
  __shared__ __align__(16) unsigned short Ps[4][16 * LD];  // wave-private P rows
  int qi = 31 - blockIdx.x;  // heaviest-first dispatch
  int h = blockIdx.y, b = blockIdx.z;
  int t = threadIdx.x;
  int w = t >> 6, lane = t & 63, quad = lane >> 4, l16 = lane & 15;
  int q0 = qi * 64;
  const unsigned short* qg = qkv + (long)(b * 2048) * 2048 + h * 64;
  const unsigned short* kg = qg + 1024;
  const unsigned short* vg = qkv + 16777216L + (((long)(b * 16 + h)) * 64) * 2048;
  unsigned short* Pw = &Ps[w][0];

  int sr = t >> 2, sc = (t & 3) * 16;
  {  // stage Q tile; each wave stages exactly its own 16 rows (wave-private)
    const unsigned short* qp = qg + (long)(q0 + sr) * 2048 + sc;
    *(int4*)(Qs + sr * LD + sc) = *(const int4*)qp;
    *(int4*)(Qs + sr * LD + sc + 8) = *(const int4*)(qp + 8);
  }
  // register prefetch of K,Vt tile 0
  int4 kv0, kv1, vv0, vv1;
  {
    const unsigned short* kp = kg + (long)sr * 2048 + sc;
    const unsigned short* vp = vg + (long)sr * 2048 + sc;
    kv0 = *(const int4*)kp; kv1 = *(const int4*)(kp + 8);
    vv0 = *(const int4*)vp; vv1 = *(const int4*)(vp + 8);
  }
  // Q frags (B-operand for S^T): [n=l16 -> q][k=quad*8+j -> s], wave-private LDS
  bf16x8 qf[2];
#pragma unroll
  for (int ks = 0; ks < 2; ++ks)
    qf[ks] = *(const bf16x8*)(Qs + (w * 16 + l16) * LD + ks * 32 + quad * 8);

  f32x4 oacc[4] = {};
  f32x4 lacc = {};
  const short ONE = 0x3F80;
  bf16x8 ones = {ONE, ONE, ONE, ONE, ONE, ONE, ONE, ONE};

  for (int kt = 0; kt <= qi; ++kt) {
    __syncthreads();
    *(int4*)(Ks + sr * LD + sc) = kv0;
    *(int4*)(Ks + sr * LD + sc + 8) = kv1;
    *(int4*)(Vts + sr * LD + sc) = vv0;
    *(int4*)(Vts + sr * LD + sc + 8) = vv1;
    __syncthreads();
    if (kt < qi) {  // prefetch next tile behind compute
      const unsigned short* kp = kg + (long)((kt + 1) * 64 + sr) * 2048 + sc;
      const unsigned short* vp = vg + (long)sr * 2048 + (kt + 1) * 64 + sc;
      kv0 = *(const int4*)kp; kv1 = *(const int4*)(kp + 8);
      vv0 = *(const int4*)vp; vv1 = *(const int4*)(vp + 8);
    }

    bool diag = (kt == qi);
    int rgmax = diag ? (w + 1) : 4;
    int kcmax = diag ? ((w >> 1) + 1) : 2;
    if (diag && !(w & 1))  // zero-pad P cols [rgmax*16, rgmax*16+16)
      *(uint2*)(Pw + l16 * LD + rgmax * 16 + quad * 4) = make_uint2(0u, 0u);

    // S^T = K x Q^T : per subtile, C col = q (l16), rows = k (quad*4+r)
#pragma unroll
    for (int rg = 0; rg < 4; ++rg) {
      if (rg >= rgmax) break;
      f32x4 st = {};
#pragma unroll
      for (int ks = 0; ks < 2; ++ks) {
        bf16x8 kf = *(const bf16x8*)(Ks + (rg * 16 + l16) * LD + ks * 32 + quad * 8);
        st = __builtin_amdgcn_mfma_f32_16x16x32_bf16(kf, qf[ks], st, 0, 0, 0);
      }
      if (diag && rg + 1 == rgmax) {  // rg == w: boundary subtile
#pragma unroll
        for (int r = 0; r < 4; ++r)
          if (quad * 4 + r > l16) st[r] = -1e30f;
      }
      unsigned int lo = ((unsigned int)f2b(exp2f(st[1])) << 16) | f2b(exp2f(st[0]));
      unsigned int hi = ((unsigned int)f2b(exp2f(st[3])) << 16) | f2b(exp2f(st[2]));
      *(uint2*)(Pw + l16 * LD + rg * 16 + quad * 4) = make_uint2(lo, hi);
    }

    // O += P V ; l += P * ones  (wave-private Ps; V frags from staged Vts)
#pragma unroll
    for (int kc = 0; kc < 2; ++kc) {
      if (kc >= kcmax) break;
      bf16x8 ap = *(const bf16x8*)(Pw + l16 * LD + kc * 32 + quad * 8);
      lacc = __builtin_amdgcn_mfma_f32_16x16x32_bf16(ap, ones, lacc, 0, 0, 0);
#pragma unroll
      for (int sg = 0; sg < 4; ++sg) {
        bf16x8 vf = *(const bf16x8*)(Vts + (sg * 16 + l16) * LD + kc * 32 + quad * 8);
        oacc[sg] = __builtin_amdgcn_mfma_f32_16x16x32_bf16(ap, vf, oacc[sg], 0, 0, 0);
      }
    }
  }

#pragma unroll
  for (int r = 0; r < 4; ++r) {
    float invl = 1.f / lacc[r];
    int row = q0 + w * 16 + quad * 4 + r;
    unsigned short* op = outp + ((long)(b * 2048 + row)) * 1024 + h * 64;
#pragma unroll
    for (int sg = 0; sg < 4; ++sg) op[sg * 16 + l16] = f2b(oacc[sg][r] * invl);
  }
}

// ---------------- residual + LayerNorm ----------------
__global__ __launch_bounds__(256) void ln_kernel(const float* __restrict__ a,
                                                 const float* __restrict__ res,
                                                 const float* __restrict__ gam,
                                                 const float* __restrict__ bet,
                                                 float* __restrict__ outf,
                                                 unsigned short* __restrict__ outb) {
  int row = blockIdx.x, t = threadIdx.x;
  float4 av = *(const float4*)(a + (long)row * 1024 + t * 4);
  float4 rv = *(const float4*)(res + (long)row * 1024 + t * 4);
  float v0 = av.x + rv.x, v1 = av.y + rv.y, v2 = av.z + rv.z, v3 = av.w + rv.w;
  float s = v0 + v1 + v2 + v3;
  float ss = v0 * v0 + v1 * v1 + v2 * v2 + v3 * v3;
#pragma unroll
  for (int off = 32; off >= 1; off >>= 1) {
    s += __shfl_down(s, off);
    ss += __shfl_down(ss, off);
  }
  __shared__ float sb[4], ssb[4];
  __shared__ float mean_s, inv_s;
  int w = t >> 6, lane = t & 63;
  if (lane == 0) { sb[w] = s; ssb[w] = ss; }
  __syncthreads();
  if (t == 0) {
    float S = sb[0] + sb[1] + sb[2] + sb[3];
    float SS = ssb[0] + ssb[1] + ssb[2] + ssb[3];
    float mean = S * (1.f / 1024.f);
    float var = SS * (1.f / 1024.f) - mean * mean;
    mean_s = mean;
    inv_s = rsqrtf(var + 1e-5f);
  }
  __syncthreads();
  float mean = mean_s, inv = inv_s;
  int c = t * 4;
  float4 gv = *(const float4*)(gam + c);
  float4 bv = *(const float4*)(bet + c);
  float y0 = (v0 - mean) * inv * gv.x + bv.x;
  float y1 = (v1 - mean) * inv * gv.y + bv.y;
  float y2 = (v2 - mean) * inv * gv.z + bv.z;
  float y3 = (v3 - mean) * inv * gv.w + bv.w;
  *(float4*)(outf + (long)row * 1024 + c) = make_float4(y0, y1, y2, y3);
  if (outb) {
    *(ushort4*)(outb + (long)row * 1024 + c) = make_ushort4(f2b(y0), f2b(y1), f2b(y2), f2b(y3));
  }
}

extern "C" void kernel_launch(void* const* d_in, const int* in_sizes, int n_in,
                              void* d_out, int out_size, void* d_ws, size_t ws_size,
                              hipStream_t stream) {
  const float* x      = (const float*)d_in[0];
  const float* w_attn = (const float*)d_in[1];
  const float* b_attn = (const float*)d_in[2];
  const float* w_proj = (const float*)d_in[3];
  const float* b_proj = (const float*)d_in[4];
  const float* ln1_g  = (const float*)d_in[5];
  const float* ln1_b  = (const float*)d_in[6];
  const float* w_ff1  = (const float*)d_in[7];
  const float* b_ff1  = (const float*)d_in[8];
  const float* w_ff2  = (const float*)d_in[9];
  const float* b_ff2  = (const float*)d_in[10];
  const float* ln2_g  = (const float*)d_in[11];
  const float* ln2_b  = (const float*)d_in[12];

  const long M = 8192, E = 1024;
  char* ws = (char*)d_ws;
  unsigned short* xb   = (unsigned short*)ws; ws += M * E * 2;           // 16 MiB
  unsigned short* wTa  = (unsigned short*)ws; ws += 3072L * 1024 * 2;    // 6
  unsigned short* wTp  = (unsigned short*)ws; ws += 1024L * 1024 * 2;    // 2
  unsigned short* wTf1 = (unsigned short*)ws; ws += 4096L * 1024 * 2;    // 8
  unsigned short* wTf2 = (unsigned short*)ws; ws += 4096L * 1024 * 2;    // 8
  unsigned short* qkvb = (unsigned short*)ws; ws += M * 3072 * 2;        // 48 (qk rows 32 MiB | vt 16 MiB)
  unsigned short* attb = (unsigned short*)ws; ws += M * E * 2;           // 16
  float* a1f = (float*)ws; ws += M * E * 4;                              // 32
  float* x1f = (float*)ws; ws += M * E * 4;                              // 32
  unsigned short* x1b = (unsigned short*)ws; ws += M * E * 2;            // 16  => 184 MiB
  unsigned short* hb = qkvb;   // overlays consumed qkv+attb space
  float* f2 = a1f;

  cvt_bf16<<<dim3((M * E) / 4 / 256), dim3(256), 0, stream>>>(x, xb, M * E);
  transpose_bf16<<<dim3(3072 / 32, 1024 / 32), dim3(32, 8), 0, stream>>>(w_attn, wTa, 1024, 3072);
  transpose_bf16<<<dim3(1024 / 32, 1024 / 32), dim3(32, 8), 0, stream>>>(w_proj, wTp, 1024, 1024);
  transpose_bf16<<<dim3(4096 / 32, 1024 / 32), dim3(32, 8), 0, stream>>>(w_ff1, wTf1, 1024, 4096);
  transpose_bf16<<<dim3(1024 / 32, 4096 / 32), dim3(32, 8), 0, stream>>>(w_ff2, wTf2, 4096, 1024);
  // qkv projection, attention-layout epilogue
  gemm_bf16<3><<<dim3(64, 24), dim3(256), 0, stream>>>(xb, wTa, b_attn, qkvb, 8192, 3072, 1024);
  // MFMA flash attention (staged, transposed-S, streaming softmax)
  attn_mfma<<<dim3(32, 16, 4), dim3(256), 0, stream>>>(qkvb, attb);
  // attn output projection
  gemm_bf16<0><<<dim3(64, 8), dim3(256), 0, stream>>>(attb, wTp, b_proj, a1f, 8192, 1024, 1024);
  ln_kernel<<<dim3(8192), dim3(256), 0, stream>>>(a1f, x, ln1_g, ln1_b, x1f, x1b);
  gemm_bf16<2><<<dim3(64, 32), dim3(256), 0, stream>>>(x1b, wTf1, b_ff1, hb, 8192, 4096, 1024);
  gemm_bf16<0><<<dim3(64, 8), dim3(256), 0, stream>>>(hb, wTf2, b_ff2, f2, 8192, 1024, 4096);
  ln_kernel<<<dim3(8192), dim3(256), 0, stream>>>(f2, x1f, ln2_g, ln2_b, (float*)d_out, nullptr);
}

// Round 6
// 617.945 us; speedup vs baseline: 1.1777x; 1.0241x over previous
//
#include <hip/hip_runtime.h>
#include <hip/hip_bf16.h>

// GPT-2 transformer block, MI355X bf16-MFMA. Round 6:
//  - attention: staged/barrier'd structure (R3 lineage) with 128 q-rows per
//    block: each staged 64-k K/V tile now feeds 36 MFMA per wave (vs 18),
//    halving barriers, staging traffic and K/V global re-reads per unit work.
//    * wave owns 32 q-rows (2 x 16 groups); Q frags resident in registers
//      (loaded once, direct global).
//    * transposed S (S^T = K x Q^T) -> packed ds_write_b64 P stores,
//      wave-private P rows; V frags read once, reused across both q-groups.
//    * wave-uniform 'active' skip on the final tile; masking only on true
//      diagonal subtiles; packed v_cvt_pk_bf16_f32 for P conversion.
//  - m=0 streaming softmax (scores O(1)), l via ones-B MFMA.
//  - GEMMs: m97 recipe (global_load_lds w=16, 128^2 tile, BK=32), unchanged.

typedef __attribute__((ext_vector_type(8))) short bf16x8;  // MFMA A/B frag
typedef __attribute__((ext_vector_type(4))) float f32x4;   // MFMA C/D frag

__device__ __forceinline__ float b2f(unsigned short u) {
  return __uint_as_float(((unsigned int)u) << 16);
}
__device__ __forceinline__ unsigned short f2b(float f) {  // RNE
  unsigned int u = __float_as_uint(f);
  u += 0x7fffu + ((u >> 16) & 1u);
  return (unsigned short)(u >> 16);
}
__device__ __forceinline__ unsigned int pk2b(float a, float b) {  // packed bf16x2
  __hip_bfloat162 h = __float22bfloat162_rn(make_float2(a, b));
  return *(unsigned int*)&h;
}
__device__ __forceinline__ void gload_lds16(const unsigned short* g, unsigned short* l) {
  __builtin_amdgcn_global_load_lds((const __attribute__((address_space(1))) void*)g,
                                   (__attribute__((address_space(3))) void*)l, 16, 0, 0);
}

// ---------------- fp32 -> bf16 elementwise ----------------
__global__ __launch_bounds__(256) void cvt_bf16(const float* __restrict__ in,
                                                unsigned short* __restrict__ out, long n) {
  long i = ((long)blockIdx.x * 256 + threadIdx.x) * 4;
  if (i >= n) return;
  float4 v = *(const float4*)(in + i);
  *(ushort4*)(out + i) = make_ushort4(f2b(v.x), f2b(v.y), f2b(v.z), f2b(v.w));
}

// ---------------- transpose fp32 [R,C] -> bf16 [C,R] ----------------
__global__ __launch_bounds__(256) void transpose_bf16(const float* __restrict__ in,
                                                      unsigned short* __restrict__ out,
                                                      int R, int C) {
  __shared__ float tile[32][33];
  int c0 = blockIdx.x * 32, r0 = blockIdx.y * 32;
  for (int i = threadIdx.y; i < 32; i += 8)
    tile[i][threadIdx.x] = in[(long)(r0 + i) * C + c0 + threadIdx.x];
  __syncthreads();
  for (int i = threadIdx.y; i < 32; i += 8)
    out[(long)(c0 + i) * R + r0 + threadIdx.x] = f2b(tile[threadIdx.x][i]);
}

// ---------------- bf16 MFMA GEMM (m97 recipe) ----------------
// EPI: 0=f32 out, 1=bf16 out, 2=bf16+relu,
//      3=qkv split: gn<2048 -> qk[m][2048] (q cols scaled by 0.125*log2e),
//                   gn>=2048 -> vt[b,h,s,t] packed ushort4 scatter.
template <int EPI>
__global__ __launch_bounds__(256) void gemm_bf16(const unsigned short* __restrict__ A,
                                                 const unsigned short* __restrict__ Bt,
                                                 const float* __restrict__ bias,
                                                 void* __restrict__ Cout,
                                                 int M, int N, int K) {
  __shared__ unsigned short As[128 * 32];
  __shared__ unsigned short Bs[128 * 32];
  int t = threadIdx.x;
  int bm = blockIdx.x * 128, bn = blockIdx.y * 128;
  int w = t >> 6, lane = t & 63;
  int wr = w >> 1, wc = w & 1, quad = lane >> 4, l16 = lane & 15;
  int srow = t >> 2, scol = (t & 3) * 8;

  const unsigned short* Ap = A + (long)(bm + srow) * K + scol;
  const unsigned short* Bp = Bt + (long)(bn + srow) * K + scol;
  unsigned short* Asw = As + w * 512;
  unsigned short* Bsw = Bs + w * 512;

  f32x4 acc[4][4] = {};

  for (int k0 = 0; k0 < K; k0 += 32) {
    __syncthreads();
    gload_lds16(Ap + k0, Asw);
    gload_lds16(Ap + (long)64 * K + k0, Asw + 2048);
    gload_lds16(Bp + k0, Bsw);
    gload_lds16(Bp + (long)64 * K + k0, Bsw + 2048);
    __syncthreads();
    bf16x8 af[4], bfr[4];
#pragma unroll
    for (int i = 0; i < 4; ++i)
      af[i] = *(const bf16x8*)(As + (wr * 64 + i * 16 + l16) * 32 + quad * 8);
#pragma unroll
    for (int j = 0; j < 4; ++j)
      bfr[j] = *(const bf16x8*)(Bs + (wc * 64 + j * 16 + l16) * 32 + quad * 8);
#pragma unroll
    for (int i = 0; i < 4; ++i)
#pragma unroll
      for (int j = 0; j < 4; ++j)
        acc[i][j] = __builtin_amdgcn_mfma_f32_16x16x32_bf16(af[i], bfr[j], acc[i][j], 0, 0, 0);
  }

#pragma unroll
  for (int i = 0; i < 4; ++i) {
#pragma unroll
    for (int j = 0; j < 4; ++j) {
      int gn = bn + wc * 64 + j * 16 + l16;
      float bv = bias[gn];
      if (EPI == 3 && gn >= 2048) {
        int h = (gn >> 6) & 15, s = gn & 63;
        int gm0 = bm + wr * 64 + i * 16 + quad * 4;
        int b = gm0 >> 11, tt0 = gm0 & 2047;
        unsigned short* vt = (unsigned short*)Cout + 16777216L;
        ushort4 us;
        us.x = f2b(acc[i][j][0] + bv);
        us.y = f2b(acc[i][j][1] + bv);
        us.z = f2b(acc[i][j][2] + bv);
        us.w = f2b(acc[i][j][3] + bv);
        *(ushort4*)(vt + (((long)(b * 16 + h)) * 64 + s) * 2048 + tt0) = us;
      } else {
#pragma unroll
        for (int r = 0; r < 4; ++r) {
          int gm = bm + wr * 64 + i * 16 + quad * 4 + r;
          float v = acc[i][j][r] + bv;
          if (EPI == 2) v = fmaxf(v, 0.f);
          if (EPI == 0) {
            ((float*)Cout)[(long)gm * N + gn] = v;
          } else if (EPI == 1 || EPI == 2) {
            ((unsigned short*)Cout)[(long)gm * N + gn] = f2b(v);
          } else {  // EPI==3, q/k rows
            float sc = (gn < 1024) ? 0.18033688011112042f : 1.0f;  // 0.125*log2(e)
            ((unsigned short*)Cout)[(long)gm * 2048 + gn] = f2b(v * sc);
          }
        }
      }
    }
  }
}

// ---------------- MFMA flash attention (staged, 128 q-rows/block) ------------
// qk[m][2048] (q cols 0..1023 pre-scaled by 0.125*log2e, k cols 1024..2047),
// vt[b,h,s,t] at elem offset 16M. Grid (T/128, H, B), 256 thr = 4 waves; wave
// w owns q rows [q0+w*32, q0+w*32+32) as two 16-row groups. P = exp2(S).
__global__ __launch_bounds__(256) void attn_mfma(const unsigned short* __restrict__ qkv,
                                                 unsigned short* __restrict__ outp) {
  const int LD = 72;  // 144 B row stride, 16B-aligned rows
  __shared__ __align__(16) unsigned short Ks[64 * LD];
  __shared__ __align__(16) unsigned short Vts[64 * LD];
  __shared__ __align__(16) unsigned short Ps[4][32 * LD];  // wave-private P rows
  int qi = 15 - blockIdx.x;  // heaviest-first dispatch
  int h = blockIdx.y, b = blockIdx.z;
  int t = threadIdx.x;
  int w = t >> 6, lane = t & 63, quad = lane >> 4, l16 = lane & 15;
  int q0 = qi * 128;
  int qw = q0 + w * 32;  // wave's first q row
  const unsigned short* qg = qkv + (long)(b * 2048) * 2048 + h * 64;
  const unsigned short* kg = qg + 1024;
  const unsigned short* vg = qkv + 16777216L + (((long)(b * 16 + h)) * 64) * 2048;
  unsigned short* Pw = &Ps[w][0];

  // Q frags (B-operand for S^T): [n=l16 -> q][k=quad*8+j -> s]; loaded once.
  bf16x8 qf[2][2];
#pragma unroll
  for (int g = 0; g < 2; ++g)
#pragma unroll
    for (int ks = 0; ks < 2; ++ks)
      qf[g][ks] = *(const bf16x8*)(qg + (long)(qw + g * 16 + l16) * 2048 + ks * 32 + quad * 8);

  int sr = t >> 2, sc = (t & 3) * 16;
  // register prefetch of K,Vt tile 0
  const unsigned short* kp = kg + (long)sr * 2048 + sc;
  const unsigned short* vp = vg + (long)sr * 2048 + sc;
  int4 kv0 = *(const int4*)kp, kv1 = *(const int4*)(kp + 8);
  int4 vv0 = *(const int4*)vp, vv1 = *(const int4*)(vp + 8);
  kp += (long)64 * 2048;
  vp += 64;

  f32x4 oacc[2][4] = {};
  f32x4 lacc[2] = {};
  const short ONE = 0x3F80;
  bf16x8 ones = {ONE, ONE, ONE, ONE, ONE, ONE, ONE, ONE};

  int lastkt = 2 * qi + 1;
  for (int kt = 0; kt <= lastkt; ++kt) {
    __syncthreads();
    *(int4*)(Ks + sr * LD + sc) = kv0;
    *(int4*)(Ks + sr * LD + sc + 8) = kv1;
    *(int4*)(Vts + sr * LD + sc) = vv0;
    *(int4*)(Vts + sr * LD + sc + 8) = vv1;
    __syncthreads();
    if (kt < lastkt) {  // prefetch next tile behind compute
      kv0 = *(const int4*)kp; kv1 = *(const int4*)(kp + 8);
      vv0 = *(const int4*)vp; vv1 = *(const int4*)(vp + 8);
      kp += (long)64 * 2048;
      vp += 64;
    }

    // wave-uniform skip: this wave needs tile only if kt*64 <= its max q row
    if (kt * 64 > qw + 31) continue;
    bool diag = (kt * 64 + 63 > qw);  // any k>q pairs for this wave?

    // S^T = K x Q^T : per subtile, C col = q (l16), rows = k (quad*4+r)
#pragma unroll
    for (int rg = 0; rg < 4; ++rg) {
      bf16x8 kf0 = *(const bf16x8*)(Ks + (rg * 16 + l16) * LD + quad * 8);
      bf16x8 kf1 = *(const bf16x8*)(Ks + (rg * 16 + l16) * LD + 32 + quad * 8);
#pragma unroll
      for (int g = 0; g < 2; ++g) {
        f32x4 st = {};
        st = __builtin_amdgcn_mfma_f32_16x16x32_bf16(kf0, qf[g][0], st, 0, 0, 0);
        st = __builtin_amdgcn_mfma_f32_16x16x32_bf16(kf1, qf[g][1], st, 0, 0, 0);
        if (diag) {
          int qglob = qw + g * 16 + l16;
          int kb = kt * 64 + rg * 16 + quad * 4;
#pragma unroll
          for (int r = 0; r < 4; ++r)
            if (kb + r > qglob) st[r] = -1e30f;
        }
        unsigned int lo = pk2b(exp2f(st[0]), exp2f(st[1]));
        unsigned int hi = pk2b(exp2f(st[2]), exp2f(st[3]));
        *(uint2*)(Pw + (g * 16 + l16) * LD + rg * 16 + quad * 4) = make_uint2(lo, hi);
      }
    }

    // V frags: read once, reuse for both q-groups
    bf16x8 vf[4][2];
#pragma unroll
    for (int sg = 0; sg < 4; ++sg)
#pragma unroll
      for (int kc = 0; kc < 2; ++kc)
        vf[sg][kc] = *(const bf16x8*)(Vts + (sg * 16 + l16) * LD + kc * 32 + quad * 8);

    // O += P V ; l += P * ones
#pragma unroll
    for (int g = 0; g < 2; ++g)
#pragma unroll
      for (int kc = 0; kc < 2; ++kc) {
        bf16x8 ap = *(const bf16x8*)(Pw + (g * 16 + l16) * LD + kc * 32 + quad * 8);
        lacc[g] = __builtin_amdgcn_mfma_f32_16x16x32_bf16(ap, ones, lacc[g], 0, 0, 0);
#pragma unroll
        for (int sg = 0; sg < 4; ++sg)
          oacc[g][sg] = __builtin_amdgcn_mfma_f32_16x16x32_bf16(ap, vf[sg][kc], oacc[g][sg], 0, 0, 0);
      }
  }

#pragma unroll
  for (int g = 0; g < 2; ++g)
#pragma unroll
    for (int r = 0; r < 4; ++r) {
      float invl = 1.f / lacc[g][r];
      int row = qw + g * 16 + quad * 4 + r;
      unsigned short* op = outp + ((long)(b * 2048 + row)) * 1024 + h * 64;
#pragma unroll
      for (int sg = 0; sg < 4; ++sg) op[sg * 16 + l16] = f2b(oacc[g][sg][r] * invl);
    }
}

// ---------------- residual + LayerNorm ----------------
__global__ __launch_bounds__(256) void ln_kernel(const float* __restrict__ a,
                                                 const float* __restrict__ res,
                                                 const float* __restrict__ gam,
                                                 const float* __restrict__ bet,
                                                 float* __restrict__ outf,
                                                 unsigned short* __restrict__ outb) {
  int row = blockIdx.x, t = threadIdx.x;
  float4 av = *(const float4*)(a + (long)row * 1024 + t * 4);
  float4 rv = *(const float4*)(res + (long)row * 1024 + t * 4);
  float v0 = av.x + rv.x, v1 = av.y + rv.y, v2 = av.z + rv.z, v3 = av.w + rv.w;
  float s = v0 + v1 + v2 + v3;
  float ss = v0 * v0 + v1 * v1 + v2 * v2 + v3 * v3;
#pragma unroll
  for (int off = 32; off >= 1; off >>= 1) {
    s += __shfl_down(s, off);
    ss += __shfl_down(ss, off);
  }
  __shared__ float sb[4], ssb[4];
  __shared__ float mean_s, inv_s;
  int w = t >> 6, lane = t & 63;
  if (lane == 0) { sb[w] = s; ssb[w] = ss; }
  __syncthreads();
  if (t == 0) {
    float S = sb[0] + sb[1] + sb[2] + sb[3];
    float SS = ssb[0] + ssb[1] + ssb[2] + ssb[3];
    float mean = S * (1.f / 1024.f);
    float var = SS * (1.f / 1024.f) - mean * mean;
    mean_s = mean;
    inv_s = rsqrtf(var + 1e-5f);
  }
  __syncthreads();
  float mean = mean_s, inv = inv_s;
  int c = t * 4;
  float4 gv = *(const float4*)(gam + c);
  float4 bv = *(const float4*)(bet + c);
  float y0 = (v0 - mean) * inv * gv.x + bv.x;
  float y1 = (v1 - mean) * inv * gv.y + bv.y;
  float y2 = (v2 - mean) * inv * gv.z + bv.z;
  float y3 = (v3 - mean) * inv * gv.w + bv.w;
  *(float4*)(outf + (long)row * 1024 + c) = make_float4(y0, y1, y2, y3);
  if (outb) {
    *(ushort4*)(outb + (long)row * 1024 + c) = make_ushort4(f2b(y0), f2b(y1), f2b(y2), f2b(y3));
  }
}

extern "C" void kernel_launch(void* const* d_in, const int* in_sizes, int n_in,
                              void* d_out, int out_size, void* d_ws, size_t ws_size,
                              hipStream_t stream) {
  const float* x      = (const float*)d_in[0];
  const float* w_attn = (const float*)d_in[1];
  const float* b_attn = (const float*)d_in[2];
  const float* w_proj = (const float*)d_in[3];
  const float* b_proj = (const float*)d_in[4];
  const float* ln1_g  = (const float*)d_in[5];
  const float* ln1_b  = (const float*)d_in[6];
  const float* w_ff1  = (const float*)d_in[7];
  const float* b_ff1  = (const float*)d_in[8];
  const float* w_ff2  = (const float*)d_in[9];
  const float* b_ff2  = (const float*)d_in[10];
  const float* ln2_g  = (const float*)d_in[11];
  const float* ln2_b  = (const float*)d_in[12];

  const long M = 8192, E = 1024;
  char* ws = (char*)d_ws;
  unsigned short* xb   = (unsigned short*)ws; ws += M * E * 2;           // 16 MiB
  unsigned short* wTa  = (unsigned short*)ws; ws += 3072L * 1024 * 2;    // 6
  unsigned short* wTp  = (unsigned short*)ws; ws += 1024L * 1024 * 2;    // 2
  unsigned short* wTf1 = (unsigned short*)ws; ws += 4096L * 1024 * 2;    // 8
  unsigned short* wTf2 = (unsigned short*)ws; ws += 4096L * 1024 * 2;    // 8
  unsigned short* qkvb = (unsigned short*)ws; ws += M * 3072 * 2;        // 48 (qk rows 32 MiB | vt 16 MiB)
  unsigned short* attb = (unsigned short*)ws; ws += M * E * 2;           // 16
  float* a1f = (float*)ws; ws += M * E * 4;                              // 32
  float* x1f = (float*)ws; ws += M * E * 4;                              // 32
  unsigned short* x1b = (unsigned short*)ws; ws += M * E * 2;            // 16  => 184 MiB
  unsigned short* hb = qkvb;   // overlays consumed qkv+attb space
  float* f2 = a1f;

  cvt_bf16<<<dim3((M * E) / 4 / 256), dim3(256), 0, stream>>>(x, xb, M * E);
  transpose_bf16<<<dim3(3072 / 32, 1024 / 32), dim3(32, 8), 0, stream>>>(w_attn, wTa, 1024, 3072);
  transpose_bf16<<<dim3(1024 / 32, 1024 / 32), dim3(32, 8), 0, stream>>>(w_proj, wTp, 1024, 1024);
  transpose_bf16<<<dim3(4096 / 32, 1024 / 32), dim3(32, 8), 0, stream>>>(w_ff1, wTf1, 1024, 4096);
  transpose_bf16<<<dim3(1024 / 32, 4096 / 32), dim3(32, 8), 0, stream>>>(w_ff2, wTf2, 4096, 1024);
  // qkv projection, attention-layout epilogue
  gemm_bf16<3><<<dim3(64, 24), dim3(256), 0, stream>>>(xb, wTa, b_attn, qkvb, 8192, 3072, 1024);
  // MFMA flash attention (staged, 128 q-rows per block)
  attn_mfma<<<dim3(16, 16, 4), dim3(256), 0, stream>>>(qkvb, attb);
  // attn output projection
  gemm_bf16<0><<<dim3(64, 8), dim3(256), 0, stream>>>(attb, wTp, b_proj, a1f, 8192, 1024, 1024);
  ln_kernel<<<dim3(8192), dim3(256), 0, stream>>>(a1f, x, ln1_g, ln1_b, x1f, x1b);
  gemm_bf16<2><<<dim3(64, 32), dim3(256), 0, stream>>>(x1b, wTf1, b_ff1, hb, 8192, 4096, 1024);
  gemm_bf16<0><<<dim3(64, 8), dim3(256), 0, stream>>>(hb, wTf2, b_ff2, f2, 8192, 1024, 4096);
  ln_kernel<<<dim3(8192), dim3(256), 0, stream>>>(f2, x1f, ln2_g, ln2_b, (float*)d_out, nullptr);
}

// Round 7
// 565.606 us; speedup vs baseline: 1.2867x; 1.0925x over previous
//
#include <hip/hip_runtime.h>
#include <hip/hip_bf16.h>

// GPT-2 transformer block, MI355X bf16-MFMA. Round 7:
//  - attention: PAIRED q-tiles for perfectly uniform block work.
//    q-tile qi costs qi+1 k-tiles (m=0 streaming softmax, causal). Block i
//    handles q-tiles {i, 31-i}: total work = 33 tiles for EVERY block -> zero
//    imbalance, no tail. Staged k-tiles 0..i serve BOTH q-tiles (double duty),
//    so block i stages only 32-i tiles.
//    * 64-row q-tiles; wave owns 16 q rows; K/V staged in LDS shared by all
//      4 waves; transposed S (S^T = K x Q^T) -> packed ds_write_b64 P stores
//      into wave-private LDS rows; l via ones-B MFMA.
//    * LDS 27.6 KB -> 5 blocks/CU cap; grid (16,16,4)=1024 uniform blocks
//      -> ~4 resident blocks/CU to hide the stage->S->exp->PV chain.
//  - GEMMs: m97 recipe (global_load_lds w=16, 128^2 tile, BK=32), unchanged.

typedef __attribute__((ext_vector_type(8))) short bf16x8;  // MFMA A/B frag
typedef __attribute__((ext_vector_type(4))) float f32x4;   // MFMA C/D frag

__device__ __forceinline__ float b2f(unsigned short u) {
  return __uint_as_float(((unsigned int)u) << 16);
}
__device__ __forceinline__ unsigned short f2b(float f) {  // RNE
  unsigned int u = __float_as_uint(f);
  u += 0x7fffu + ((u >> 16) & 1u);
  return (unsigned short)(u >> 16);
}
__device__ __forceinline__ unsigned int pk2b(float a, float b) {  // packed bf16x2
  __hip_bfloat162 h = __float22bfloat162_rn(make_float2(a, b));
  return *(unsigned int*)&h;
}
__device__ __forceinline__ void gload_lds16(const unsigned short* g, unsigned short* l) {
  __builtin_amdgcn_global_load_lds((const __attribute__((address_space(1))) void*)g,
                                   (__attribute__((address_space(3))) void*)l, 16, 0, 0);
}

// ---------------- fp32 -> bf16 elementwise ----------------
__global__ __launch_bounds__(256) void cvt_bf16(const float* __restrict__ in,
                                                unsigned short* __restrict__ out, long n) {
  long i = ((long)blockIdx.x * 256 + threadIdx.x) * 4;
  if (i >= n) return;
  float4 v = *(const float4*)(in + i);
  *(ushort4*)(out + i) = make_ushort4(f2b(v.x), f2b(v.y), f2b(v.z), f2b(v.w));
}

// ---------------- transpose fp32 [R,C] -> bf16 [C,R] ----------------
__global__ __launch_bounds__(256) void transpose_bf16(const float* __restrict__ in,
                                                      unsigned short* __restrict__ out,
                                                      int R, int C) {
  __shared__ float tile[32][33];
  int c0 = blockIdx.x * 32, r0 = blockIdx.y * 32;
  for (int i = threadIdx.y; i < 32; i += 8)
    tile[i][threadIdx.x] = in[(long)(r0 + i) * C + c0 + threadIdx.x];
  __syncthreads();
  for (int i = threadIdx.y; i < 32; i += 8)
    out[(long)(c0 + i) * R + r0 + threadIdx.x] = f2b(tile[threadIdx.x][i]);
}

// ---------------- bf16 MFMA GEMM (m97 recipe) ----------------
// EPI: 0=f32 out, 1=bf16 out, 2=bf16+relu,
//      3=qkv split: gn<2048 -> qk[m][2048] (q cols scaled by 0.125*log2e),
//                   gn>=2048 -> vt[b,h,s,t] packed ushort4 scatter.
template <int EPI>
__global__ __launch_bounds__(256) void gemm_bf16(const unsigned short* __restrict__ A,
                                                 const unsigned short* __restrict__ Bt,
                                                 const float* __restrict__ bias,
                                                 void* __restrict__ Cout,
                                                 int M, int N, int K) {
  __shared__ unsigned short As[128 * 32];
  __shared__ unsigned short Bs[128 * 32];
  int t = threadIdx.x;
  int bm = blockIdx.x * 128, bn = blockIdx.y * 128;
  int w = t >> 6, lane = t & 63;
  int wr = w >> 1, wc = w & 1, quad = lane >> 4, l16 = lane & 15;
  int srow = t >> 2, scol = (t & 3) * 8;

  const unsigned short* Ap = A + (long)(bm + srow) * K + scol;
  const unsigned short* Bp = Bt + (long)(bn + srow) * K + scol;
  unsigned short* Asw = As + w * 512;
  unsigned short* Bsw = Bs + w * 512;

  f32x4 acc[4][4] = {};

  for (int k0 = 0; k0 < K; k0 += 32) {
    __syncthreads();
    gload_lds16(Ap + k0, Asw);
    gload_lds16(Ap + (long)64 * K + k0, Asw + 2048);
    gload_lds16(Bp + k0, Bsw);
    gload_lds16(Bp + (long)64 * K + k0, Bsw + 2048);
    __syncthreads();
    bf16x8 af[4], bfr[4];
#pragma unroll
    for (int i = 0; i < 4; ++i)
      af[i] = *(const bf16x8*)(As + (wr * 64 + i * 16 + l16) * 32 + quad * 8);
#pragma unroll
    for (int j = 0; j < 4; ++j)
      bfr[j] = *(const bf16x8*)(Bs + (wc * 64 + j * 16 + l16) * 32 + quad * 8);
#pragma unroll
    for (int i = 0; i < 4; ++i)
#pragma unroll
      for (int j = 0; j < 4; ++j)
        acc[i][j] = __builtin_amdgcn_mfma_f32_16x16x32_bf16(af[i], bfr[j], acc[i][j], 0, 0, 0);
  }

#pragma unroll
  for (int i = 0; i < 4; ++i) {
#pragma unroll
    for (int j = 0; j < 4; ++j) {
      int gn = bn + wc * 64 + j * 16 + l16;
      float bv = bias[gn];
      if (EPI == 3 && gn >= 2048) {
        int h = (gn >> 6) & 15, s = gn & 63;
        int gm0 = bm + wr * 64 + i * 16 + quad * 4;
        int b = gm0 >> 11, tt0 = gm0 & 2047;
        unsigned short* vt = (unsigned short*)Cout + 16777216L;
        ushort4 us;
        us.x = f2b(acc[i][j][0] + bv);
        us.y = f2b(acc[i][j][1] + bv);
        us.z = f2b(acc[i][j][2] + bv);
        us.w = f2b(acc[i][j][3] + bv);
        *(ushort4*)(vt + (((long)(b * 16 + h)) * 64 + s) * 2048 + tt0) = us;
      } else {
#pragma unroll
        for (int r = 0; r < 4; ++r) {
          int gm = bm + wr * 64 + i * 16 + quad * 4 + r;
          float v = acc[i][j][r] + bv;
          if (EPI == 2) v = fmaxf(v, 0.f);
          if (EPI == 0) {
            ((float*)Cout)[(long)gm * N + gn] = v;
          } else if (EPI == 1 || EPI == 2) {
            ((unsigned short*)Cout)[(long)gm * N + gn] = f2b(v);
          } else {  // EPI==3, q/k rows
            float sc = (gn < 1024) ? 0.18033688011112042f : 1.0f;  // 0.125*log2(e)
            ((unsigned short*)Cout)[(long)gm * 2048 + gn] = f2b(v * sc);
          }
        }
      }
    }
  }
}

// ---------------- MFMA flash attention (paired q-tiles, uniform work) --------
// qk[m][2048] (q cols 0..1023 pre-scaled by 0.125*log2e, k cols 1024..2047),
// vt[b,h,s,t] at elem offset 16M. Grid (16, H, B), 256 thr = 4 waves; block i
// handles q-tiles qa=i and qb=31-i (33 tile-works each, uniform). Wave w owns
// q rows [qt*64+w*16, +16). P = exp2(S); l via ones-B MFMA.
__global__ __launch_bounds__(256) void attn_mfma(const unsigned short* __restrict__ qkv,
                                                 unsigned short* __restrict__ outp) {
  const int LD = 72;  // 144 B row stride; b64/b128 accesses land 2-way (free)
  __shared__ __align__(16) unsigned short Ks[64 * LD];
  __shared__ __align__(16) unsigned short Vts[64 * LD];
  __shared__ __align__(16) unsigned short Ps[4][16 * LD];  // wave-private P rows
  int qa = blockIdx.x, qb = 31 - qa;  // paired q-tiles
  int h = blockIdx.y, b = blockIdx.z;
  int t = threadIdx.x;
  int w = t >> 6, lane = t & 63, quad = lane >> 4, l16 = lane & 15;
  const unsigned short* qg = qkv + (long)(b * 2048) * 2048 + h * 64;
  const unsigned short* kg = qg + 1024;
  const unsigned short* vg = qkv + 16777216L + (((long)(b * 16 + h)) * 64) * 2048;
  unsigned short* Pw = &Ps[w][0];

  // Q frags for both q-tiles (B-operand for S^T): [n=l16 -> q][k=quad*8+j -> s]
  bf16x8 qfa[2], qfb[2];
#pragma unroll
  for (int ks = 0; ks < 2; ++ks) {
    qfa[ks] = *(const bf16x8*)(qg + (long)(qa * 64 + w * 16 + l16) * 2048 + ks * 32 + quad * 8);
    qfb[ks] = *(const bf16x8*)(qg + (long)(qb * 64 + w * 16 + l16) * 2048 + ks * 32 + quad * 8);
  }

  int sr = t >> 2, sc = (t & 3) * 16;
  const unsigned short* kp = kg + (long)sr * 2048 + sc;
  const unsigned short* vp = vg + (long)sr * 2048 + sc;
  int4 kv0 = *(const int4*)kp, kv1 = *(const int4*)(kp + 8);
  int4 vv0 = *(const int4*)vp, vv1 = *(const int4*)(vp + 8);
  kp += (long)64 * 2048;
  vp += 64;

  f32x4 oa[4] = {}, ob[4] = {};
  f32x4 la = {}, lb = {};
  const short ONE = 0x3F80;
  bf16x8 ones = {ONE, ONE, ONE, ONE, ONE, ONE, ONE, ONE};

  // per-tile work for one q-tile: S^T subtiles -> exp2 -> P (LDS) -> PV + l
  auto process = [&](const bf16x8* qf, int qt, int kt, f32x4* oacc, f32x4& lacc) {
    bool diag = (kt == qt);
#pragma unroll
    for (int rg = 0; rg < 4; ++rg) {
      bf16x8 kf0 = *(const bf16x8*)(Ks + (rg * 16 + l16) * LD + quad * 8);
      bf16x8 kf1 = *(const bf16x8*)(Ks + (rg * 16 + l16) * LD + 32 + quad * 8);
      f32x4 st = {};
      st = __builtin_amdgcn_mfma_f32_16x16x32_bf16(kf0, qf[0], st, 0, 0, 0);
      st = __builtin_amdgcn_mfma_f32_16x16x32_bf16(kf1, qf[1], st, 0, 0, 0);
      if (diag) {
        int kq = rg * 16 + quad * 4;  // k row within tile
        int qq = w * 16 + l16;        // q row within tile
#pragma unroll
        for (int r = 0; r < 4; ++r)
          if (kq + r > qq) st[r] = -1e30f;
      }
      unsigned int lo = pk2b(exp2f(st[0]), exp2f(st[1]));
      unsigned int hi = pk2b(exp2f(st[2]), exp2f(st[3]));
      *(uint2*)(Pw + l16 * LD + rg * 16 + quad * 4) = make_uint2(lo, hi);
    }
#pragma unroll
    for (int kc = 0; kc < 2; ++kc) {
      bf16x8 ap = *(const bf16x8*)(Pw + l16 * LD + kc * 32 + quad * 8);
      lacc = __builtin_amdgcn_mfma_f32_16x16x32_bf16(ap, ones, lacc, 0, 0, 0);
#pragma unroll
      for (int sg = 0; sg < 4; ++sg) {
        bf16x8 vf = *(const bf16x8*)(Vts + (sg * 16 + l16) * LD + kc * 32 + quad * 8);
        oacc[sg] = __builtin_amdgcn_mfma_f32_16x16x32_bf16(ap, vf, oacc[sg], 0, 0, 0);
      }
    }
  };

  for (int kt = 0; kt <= qb; ++kt) {
    __syncthreads();
    *(int4*)(Ks + sr * LD + sc) = kv0;
    *(int4*)(Ks + sr * LD + sc + 8) = kv1;
    *(int4*)(Vts + sr * LD + sc) = vv0;
    *(int4*)(Vts + sr * LD + sc + 8) = vv1;
    __syncthreads();
    if (kt < qb) {  // prefetch next tile behind compute
      kv0 = *(const int4*)kp; kv1 = *(const int4*)(kp + 8);
      vv0 = *(const int4*)vp; vv1 = *(const int4*)(vp + 8);
      kp += (long)64 * 2048;
      vp += 64;
    }
    process(qfb, qb, kt, ob, lb);          // heavy tile: every kt
    if (kt <= qa) process(qfa, qa, kt, oa, la);  // light tile: double-duty stage
  }

  auto epi = [&](int qt, f32x4* oacc, f32x4& lacc) {
#pragma unroll
    for (int r = 0; r < 4; ++r) {
      float invl = 1.f / lacc[r];
      int row = qt * 64 + w * 16 + quad * 4 + r;
      unsigned short* op = outp + ((long)(b * 2048 + row)) * 1024 + h * 64;
#pragma unroll
      for (int sg = 0; sg < 4; ++sg) op[sg * 16 + l16] = f2b(oacc[sg][r] * invl);
    }
  };
  epi(qa, oa, la);
  epi(qb, ob, lb);
}

// ---------------- residual + LayerNorm ----------------
__global__ __launch_bounds__(256) void ln_kernel(const float* __restrict__ a,
                                                 const float* __restrict__ res,
                                                 const float* __restrict__ gam,
                                                 const float* __restrict__ bet,
                                                 float* __restrict__ outf,
                                                 unsigned short* __restrict__ outb) {
  int row = blockIdx.x, t = threadIdx.x;
  float4 av = *(const float4*)(a + (long)row * 1024 + t * 4);
  float4 rv = *(const float4*)(res + (long)row * 1024 + t * 4);
  float v0 = av.x + rv.x, v1 = av.y + rv.y, v2 = av.z + rv.z, v3 = av.w + rv.w;
  float s = v0 + v1 + v2 + v3;
  float ss = v0 * v0 + v1 * v1 + v2 * v2 + v3 * v3;
#pragma unroll
  for (int off = 32; off >= 1; off >>= 1) {
    s += __shfl_down(s, off);
    ss += __shfl_down(ss, off);
  }
  __shared__ float sb[4], ssb[4];
  __shared__ float mean_s, inv_s;
  int w = t >> 6, lane = t & 63;
  if (lane == 0) { sb[w] = s; ssb[w] = ss; }
  __syncthreads();
  if (t == 0) {
    float S = sb[0] + sb[1] + sb[2] + sb[3];
    float SS = ssb[0] + ssb[1] + ssb[2] + ssb[3];
    float mean = S * (1.f / 1024.f);
    float var = SS * (1.f / 1024.f) - mean * mean;
    mean_s = mean;
    inv_s = rsqrtf(var + 1e-5f);
  }
  __syncthreads();
  float mean = mean_s, inv = inv_s;
  int c = t * 4;
  float4 gv = *(const float4*)(gam + c);
  float4 bv = *(const float4*)(bet + c);
  float y0 = (v0 - mean) * inv * gv.x + bv.x;
  float y1 = (v1 - mean) * inv * gv.y + bv.y;
  float y2 = (v2 - mean) * inv * gv.z + bv.z;
  float y3 = (v3 - mean) * inv * gv.w + bv.w;
  *(float4*)(outf + (long)row * 1024 + c) = make_float4(y0, y1, y2, y3);
  if (outb) {
    *(ushort4*)(outb + (long)row * 1024 + c) = make_ushort4(f2b(y0), f2b(y1), f2b(y2), f2b(y3));
  }
}

extern "C" void kernel_launch(void* const* d_in, const int* in_sizes, int n_in,
                              void* d_out, int out_size, void* d_ws, size_t ws_size,
                              hipStream_t stream) {
  const float* x      = (const float*)d_in[0];
  const float* w_attn = (const float*)d_in[1];
  const float* b_attn = (const float*)d_in[2];
  const float* w_proj = (const float*)d_in[3];
  const float* b_proj = (const float*)d_in[4];
  const float* ln1_g  = (const float*)d_in[5];
  const float* ln1_b  = (const float*)d_in[6];
  const float* w_ff1  = (const float*)d_in[7];
  const float* b_ff1  = (const float*)d_in[8];
  const float* w_ff2  = (const float*)d_in[9];
  const float* b_ff2  = (const float*)d_in[10];
  const float* ln2_g  = (const float*)d_in[11];
  const float* ln2_b  = (const float*)d_in[12];

  const long M = 8192, E = 1024;
  char* ws = (char*)d_ws;
  unsigned short* xb   = (unsigned short*)ws; ws += M * E * 2;           // 16 MiB
  unsigned short* wTa  = (unsigned short*)ws; ws += 3072L * 1024 * 2;    // 6
  unsigned short* wTp  = (unsigned short*)ws; ws += 1024L * 1024 * 2;    // 2
  unsigned short* wTf1 = (unsigned short*)ws; ws += 4096L * 1024 * 2;    // 8
  unsigned short* wTf2 = (unsigned short*)ws; ws += 4096L * 1024 * 2;    // 8
  unsigned short* qkvb = (unsigned short*)ws; ws += M * 3072 * 2;        // 48 (qk rows 32 MiB | vt 16 MiB)
  unsigned short* attb = (unsigned short*)ws; ws += M * E * 2;           // 16
  float* a1f = (float*)ws; ws += M * E * 4;                              // 32
  float* x1f = (float*)ws; ws += M * E * 4;                              // 32
  unsigned short* x1b = (unsigned short*)ws; ws += M * E * 2;            // 16  => 184 MiB
  unsigned short* hb = qkvb;   // overlays consumed qkv+attb space
  float* f2 = a1f;

  cvt_bf16<<<dim3((M * E) / 4 / 256), dim3(256), 0, stream>>>(x, xb, M * E);
  transpose_bf16<<<dim3(3072 / 32, 1024 / 32), dim3(32, 8), 0, stream>>>(w_attn, wTa, 1024, 3072);
  transpose_bf16<<<dim3(1024 / 32, 1024 / 32), dim3(32, 8), 0, stream>>>(w_proj, wTp, 1024, 1024);
  transpose_bf16<<<dim3(4096 / 32, 1024 / 32), dim3(32, 8), 0, stream>>>(w_ff1, wTf1, 1024, 4096);
  transpose_bf16<<<dim3(1024 / 32, 4096 / 32), dim3(32, 8), 0, stream>>>(w_ff2, wTf2, 4096, 1024);
  // qkv projection, attention-layout epilogue
  gemm_bf16<3><<<dim3(64, 24), dim3(256), 0, stream>>>(xb, wTa, b_attn, qkvb, 8192, 3072, 1024);
  // MFMA flash attention (paired q-tiles, uniform work)
  attn_mfma<<<dim3(16, 16, 4), dim3(256), 0, stream>>>(qkvb, attb);
  // attn output projection
  gemm_bf16<0><<<dim3(64, 8), dim3(256), 0, stream>>>(attb, wTp, b_proj, a1f, 8192, 1024, 1024);
  ln_kernel<<<dim3(8192), dim3(256), 0, stream>>>(a1f, x, ln1_g, ln1_b, x1f, x1b);
  gemm_bf16<2><<<dim3(64, 32), dim3(256), 0, stream>>>(x1b, wTf1, b_ff1, hb, 8192, 4096, 1024);
  gemm_bf16<0><<<dim3(64, 8), dim3(256), 0, stream>>>(hb, wTf2, b_ff2, f2, 8192, 1024, 4096);
  ln_kernel<<<dim3(8192), dim3(256), 0, stream>>>(f2, x1f, ln2_g, ln2_b, (float*)d_out, nullptr);
}